// Round 1
// baseline (2484.053 us; speedup 1.0000x reference)
//
#include <hip/hip_runtime.h>
#include <math.h>

#define BB 32768
#define BN 20
#define DD 172
#define TT 100
#define EE 272
#define HD2 136
#define BT 16

// Generic tiled mat-vec batch: OUT[i][e] = act(bias[e] + sum_k A[i][k] * W[e*ldw + kcol0 + k])
// i in [0,BT), e in [0,NO). 256 threads: lane eo = t&63 handles e in {eo, eo+64, eo+128, ...}
// paired two at a time; group ig = t>>6 handles 4 batch rows i0..i0+3.
__device__ __forceinline__ void gemm_rowW(
    const float* __restrict__ W, int ldw, int kcol0,
    const float* __restrict__ bias,          // may be null
    const float* __restrict__ A, int lda,    // A[i*lda + k]; lda may be 0 (broadcast row)
    int K,
    float* OUT, int ldo, int NO,
    bool accum, int act,                     // act: 0 none, 1 relu, 2 zero-if-invalid
    const int* __restrict__ inval,
    float* __restrict__ gout, int gld,       // if non-null write here instead of OUT
    int t)
{
  const int eo = t & 63;
  const int i0 = (t >> 6) * 4;
  for (int e = eo; e < NO; e += 128) {
    const int e2 = e + 64;
    const bool has2 = (e2 < NO);
    float acc[4][2];
    const float b1 = (!accum && bias) ? bias[e] : 0.f;
    const float b2 = (!accum && bias && has2) ? bias[e2] : 0.f;
#pragma unroll
    for (int ii = 0; ii < 4; ii++) {
      acc[ii][0] = accum ? OUT[(i0 + ii) * ldo + e] : b1;
      acc[ii][1] = has2 ? (accum ? OUT[(i0 + ii) * ldo + e2] : b2) : 0.f;
    }
    const float* w1 = W + (size_t)e * ldw + kcol0;
    const float* w2 = W + (size_t)e2 * ldw + kcol0;
    for (int k = 0; k < K; k += 4) {
      const float4 wq1 = *(const float4*)(w1 + k);
      float4 wq2 = make_float4(0.f, 0.f, 0.f, 0.f);
      if (has2) wq2 = *(const float4*)(w2 + k);
#pragma unroll
      for (int ii = 0; ii < 4; ii++) {
        const float4 a = *(const float4*)(A + (size_t)(i0 + ii) * lda + k);
        acc[ii][0] += a.x * wq1.x + a.y * wq1.y + a.z * wq1.z + a.w * wq1.w;
        acc[ii][1] += a.x * wq2.x + a.y * wq2.y + a.z * wq2.z + a.w * wq2.w;
      }
    }
#pragma unroll
    for (int ii = 0; ii < 4; ii++) {
      float v1 = acc[ii][0], v2 = acc[ii][1];
      if (act == 1) { v1 = fmaxf(v1, 0.f); v2 = fmaxf(v2, 0.f); }
      else if (act == 2) { if (inval[i0 + ii]) { v1 = 0.f; v2 = 0.f; } }
      if (gout) {
        gout[(i0 + ii) * gld + e] = v1;
        if (has2) gout[(i0 + ii) * gld + e2] = v2;
      } else {
        OUT[(i0 + ii) * ldo + e] = v1;
        if (has2) OUT[(i0 + ii) * ldo + e2] = v2;
      }
    }
  }
}

// Column variant: OUT[i][j] = sum_d A[i][d] * W[d*ldw + j] (W pre-offset to its first row).
// Reduction strides down rows; lanes j are consecutive -> coalesced weight reads.
__device__ __forceinline__ void gemm_colW(
    const float* __restrict__ W, int ldw,
    const float* __restrict__ A, int lda,
    int K,
    float* OUT, int ldo, int NO,
    int t)
{
  const int eo = t & 63;
  const int i0 = (t >> 6) * 4;
  for (int j = eo; j < NO; j += 128) {
    const int j2 = j + 64;
    const bool has2 = (j2 < NO);
    float acc[4][2];
#pragma unroll
    for (int ii = 0; ii < 4; ii++) { acc[ii][0] = 0.f; acc[ii][1] = 0.f; }
    for (int d = 0; d < K; d += 4) {
      const float* wr = W + (size_t)d * ldw;
      const float w10 = wr[j];
      const float w11 = wr[ldw + j];
      const float w12 = wr[2 * ldw + j];
      const float w13 = wr[3 * ldw + j];
      float w20 = 0.f, w21 = 0.f, w22 = 0.f, w23 = 0.f;
      if (has2) { w20 = wr[j2]; w21 = wr[ldw + j2]; w22 = wr[2 * ldw + j2]; w23 = wr[3 * ldw + j2]; }
#pragma unroll
      for (int ii = 0; ii < 4; ii++) {
        const float4 a = *(const float4*)(A + (size_t)(i0 + ii) * lda + d);
        acc[ii][0] += a.x * w10 + a.y * w11 + a.z * w12 + a.w * w13;
        acc[ii][1] += a.x * w20 + a.y * w21 + a.z * w22 + a.w * w23;
      }
    }
#pragma unroll
    for (int ii = 0; ii < 4; ii++) {
      OUT[(i0 + ii) * ldo + j] = acc[ii][0];
      if (has2) OUT[(i0 + ii) * ldo + j2] = acc[ii][1];
    }
  }
}

__global__ __launch_bounds__(256, 2)
void attn_msg_agg_fused(const float* __restrict__ msg,
                        const float* __restrict__ timeb,
                        const float* __restrict__ tw_g,
                        const float* __restrict__ tb_g,
                        const float* __restrict__ ipw,
                        const float* __restrict__ ipb,
                        const float* __restrict__ opw,
                        const float* __restrict__ opb,
                        const float* __restrict__ f1w,
                        const float* __restrict__ f1b,
                        const float* __restrict__ f2w,
                        const float* __restrict__ f2b,
                        float* __restrict__ outg)
{
  __shared__ __align__(16) float s_q[BT * EE];          // q -> ctx -> h1      (17.4 KB)
  __shared__ __align__(16) float s_qk[BT * 2 * EE];     // qk -> mbar -> attn_out (34.8 KB)
  __shared__ __align__(16) float s_attn[BT * 2 * BN];
  __shared__ __align__(16) float s_delta[BT * BN];
  __shared__ __align__(16) float s_tw[TT];
  __shared__ __align__(16) float s_tb[TT];
  __shared__ __align__(16) float s_tfl[TT];
  __shared__ float s_sconst[BT * 2];
  __shared__ unsigned s_mask[BT];
  __shared__ int s_inval[BT];

  const int t = threadIdx.x;
  const int base = blockIdx.x * BT;

  // ---- P0: time features, mask, delta ----
  if (t < TT) {
    const float b = tb_g[t];
    s_tw[t] = tw_g[t];
    s_tb[t] = b;
    s_tfl[t] = __cosf(b);          // tf at n = N-1 (delta = 0), batch-constant
  }
  for (int idx = t; idx < BT * BN; idx += 256)
    s_delta[idx] = timeb[(size_t)base * BN + idx];
  __syncthreads();
  if (t < BT) {
    const float st = s_delta[t * BN + BN - 1];
    unsigned m = 0;
#pragma unroll
    for (int n = 0; n < BN; n++) {
      const float v = s_delta[t * BN + n];
      if (v < 0.f) m |= (1u << n);
      s_delta[t * BN + n] = v - st;
    }
    const int inv = (m == ((1u << BN) - 1u)) ? 1 : 0;
    if (inv) m &= ~1u;             // mask[0] forced False when all-masked
    s_mask[t] = m;
    s_inval[t] = inv;
  }
  __syncthreads();

  // ---- P1: q = [source, tf_last] @ Wq^T + bq ----
  const float* srcA = msg + (size_t)base * BN * DD + (size_t)(BN - 1) * DD;  // A[i*3440 + k]
  gemm_rowW(ipw, EE, 0, ipb, srcA, BN * DD, DD, s_q, EE, EE, false, 0, nullptr, nullptr, 0, t);
  gemm_rowW(ipw, EE, DD, nullptr, s_tfl, 0, TT, s_q, EE, EE, true, 0, nullptr, nullptr, 0, t);
  __syncthreads();

  // ---- P2: qk[h] = q[h] @ Wk_h (fold q into Wk), sconst[h] = q[h].bk_h ----
  if (t < BT * 2) {
    const int i = t >> 1, h = t & 1;
    const float* qv = s_q + i * EE + h * HD2;
    const float* bk = ipb + EE + h * HD2;
    float s = 0.f;
    for (int d = 0; d < HD2; d++) s += qv[d] * bk[d];
    s_sconst[t] = s;
  }
  gemm_colW(ipw + (size_t)EE * EE, EE, s_q, EE, HD2, s_qk, 2 * EE, EE, t);
  gemm_colW(ipw + (size_t)(EE + HD2) * EE, EE, s_q + HD2, EE, HD2, s_qk + EE, 2 * EE, EE, t);
  __syncthreads();

  // ---- P3: scores[i][h][n] = msgs_un[i][n] . qk[i][h] + sconst, mask, scale ----
  const float scale = 0.08574929257125442f;  // 1/sqrt(136)
  for (int o = t; o < BT * 2 * BN; o += 256) {
    const int i = o / (2 * BN);
    const int r = o % (2 * BN);
    const int h = r / BN;
    const int n = r % BN;
    const float* mrow = msg + ((size_t)(base + i) * BN + n) * DD;
    const float* qkv = s_qk + i * 2 * EE + h * EE;
    float s = s_sconst[i * 2 + h];
    for (int d = 0; d < DD; d += 4) {
      const float4 m4 = *(const float4*)(mrow + d);
      const float4 q4 = *(const float4*)(qkv + d);
      s += m4.x * q4.x + m4.y * q4.y + m4.z * q4.z + m4.w * q4.w;
    }
    const float del = s_delta[i * BN + n];
    const float* qkt = qkv + DD;
    for (int u = 0; u < TT; u++)
      s += __cosf(del * s_tw[u] + s_tb[u]) * qkt[u];
    const bool masked = (s_mask[i] >> n) & 1u;
    s_attn[o] = masked ? -1e9f : s * scale;
  }
  __syncthreads();

  // ---- P3b: softmax over n per (i,h) ----
  if (t < BT * 2) {
    float* sc = s_attn + t * BN;
    float m = -3.4e38f;
#pragma unroll
    for (int n = 0; n < BN; n++) m = fmaxf(m, sc[n]);
    float sum = 0.f;
#pragma unroll
    for (int n = 0; n < BN; n++) { const float e = __expf(sc[n] - m); sc[n] = e; sum += e; }
    const float inv = 1.f / sum;
#pragma unroll
    for (int n = 0; n < BN; n++) sc[n] *= inv;
  }
  __syncthreads();

  // ---- P4: mbar[i][h][j] = sum_n attn * msgs_un[i][n][j]  (overwrites qk) ----
  for (int o = t; o < BT * 2 * EE; o += 256) {
    const int i = o / (2 * EE);
    const int r = o % (2 * EE);
    const int h = r / EE;
    const int j = r % EE;
    const float* at = s_attn + (i * 2 + h) * BN;
    float acc = 0.f;
    if (j < DD) {
      const float* mp = msg + (size_t)(base + i) * BN * DD + j;
#pragma unroll
      for (int n = 0; n < BN; n++) acc += at[n] * mp[n * DD];
    } else {
      const int u = j - DD;
      const float w = s_tw[u], b = s_tb[u];
#pragma unroll
      for (int n = 0; n < BN; n++) acc += at[n] * __cosf(s_delta[i * BN + n] * w + b);
    }
    s_qk[o] = acc;
  }
  __syncthreads();

  // ---- P5: ctx[h] = mbar[h] @ Wv_h^T + bv_h  (V folded through attn mean) ----
  gemm_rowW(ipw + (size_t)(2 * EE) * EE, EE, 0, ipb + 2 * EE,
            s_qk, 2 * EE, EE, s_q, EE, HD2, false, 0, nullptr, nullptr, 0, t);
  gemm_rowW(ipw + (size_t)(2 * EE + HD2) * EE, EE, 0, ipb + 2 * EE + HD2,
            s_qk + EE, 2 * EE, EE, s_q + HD2, EE, HD2, false, 0, nullptr, nullptr, 0, t);
  __syncthreads();

  // ---- P6: attn_out = ctx @ Wo^T + bo, zeroed if invalid -> s_qk[:, :272] ----
  gemm_rowW(opw, EE, 0, opb, s_q, EE, EE, s_qk, 2 * EE, EE, false, 2, s_inval, nullptr, 0, t);
  __syncthreads();

  // ---- P7: h1 = relu([attn_out, source] @ fc1^T + b1) -> s_q[:, :172] ----
  gemm_rowW(f1w, EE + DD, 0, f1b, s_qk, 2 * EE, EE, s_q, EE, DD, false, 0, nullptr, nullptr, 0, t);
  gemm_rowW(f1w, EE + DD, EE, nullptr, srcA, BN * DD, DD, s_q, EE, DD, true, 1, nullptr, nullptr, 0, t);
  __syncthreads();

  // ---- P8: out = h1 @ fc2^T + b2 -> global ----
  gemm_rowW(f2w, DD, 0, f2b, s_q, EE, DD, nullptr, 0, DD, false, 0, nullptr,
            outg + (size_t)base * DD, DD, t);
}

extern "C" void kernel_launch(void* const* d_in, const int* in_sizes, int n_in,
                              void* d_out, int out_size, void* d_ws, size_t ws_size,
                              hipStream_t stream) {
  const float* msg  = (const float*)d_in[0];
  const float* tb   = (const float*)d_in[1];
  // d_in[2] (memory) is unused by the reference
  const float* tw_g = (const float*)d_in[3];
  const float* tb_g = (const float*)d_in[4];
  const float* ipw  = (const float*)d_in[5];
  const float* ipb  = (const float*)d_in[6];
  const float* opw  = (const float*)d_in[7];
  const float* opb  = (const float*)d_in[8];
  const float* f1w  = (const float*)d_in[9];
  const float* f1b  = (const float*)d_in[10];
  const float* f2w  = (const float*)d_in[11];
  const float* f2b  = (const float*)d_in[12];
  float* outg = (float*)d_out;

  dim3 grid(BB / BT), block(256);
  hipLaunchKernelGGL(attn_msg_agg_fused, grid, block, 0, stream,
                     msg, tb, tw_g, tb_g, ipw, ipb, opw, opb, f1w, f1b, f2w, f2b, outg);
}